// Round 8
// baseline (420.746 us; speedup 1.0000x reference)
//
#include <hip/hip_runtime.h>
#include <stdint.h>

#define D 256

typedef __attribute__((ext_vector_type(8))) short bf16x8;
typedef __attribute__((ext_vector_type(4))) float f32x4;

__device__ inline unsigned short f2bf(float f) {
    union { float f; uint32_t u; } v; v.f = f;
    return (unsigned short)((v.u + 0x7FFFu + ((v.u >> 16) & 1u)) >> 16);
}
__device__ inline float bf2f(unsigned short b) {
    return __uint_as_float(((uint32_t)b) << 16);
}
__device__ inline float bflo(unsigned int u) { return __uint_as_float(u << 16); }
__device__ inline float bfhi(unsigned int u) { return __uint_as_float(u & 0xffff0000u); }

// segment geometry (padded to 1024-multiples for the block scan)
#define SEG0 0
#define SEG1 50176
#define SEG2 62464
#define CURTOT 66560          // 50176+12288+4096
#define NBLK 65               // seg0 blocks 0-48, seg1 49-60, seg2 61-64

#define WBLK 1536             // 6*65536/256

// ---------- fused preprocessing: weights transpose + edge count --------------
struct PreArgs {
    const float* w[6];
    unsigned short* wt;
    const int* d0; const int* d1; const int* d2;
    int* cur;
    int E0, E01, Etot;
};

__global__ __launch_bounds__(256) void fused_pre(PreArgs a)
{
    int b = blockIdx.x;
    if (b < WBLK) {
        int t = b * 256 + threadIdx.x;
        int m = t >> 16, e = t & 65535;
        int col = e >> 8, k = e & 255;
        a.wt[t] = f2bf(a.w[m][(k << 8) + col]);
    } else {
        int e = (b - WBLK) * 256 + threadIdx.x;
        if (e >= a.Etot) return;
        int base, d;
        if (e < a.E0)       { base = SEG0; d = a.d0[e]; }
        else if (e < a.E01) { base = SEG1; d = a.d1[e - a.E0]; }
        else                { base = SEG2; d = a.d2[e - a.E01]; }
        atomicAdd(&a.cur[base + d], 1);
    }
}

// ---------- single-pass segmented scan with decoupled lookback ---------------
// 65 blocks, all co-resident (<< 256 CUs). flag[b] = segment-inclusive prefix
// through block b, +1 (0 = not ready). Chains reset at segment starts.
__global__ __launch_bounds__(256) void scan_lookback(
    int* __restrict__ cur, unsigned int* __restrict__ flag)
{
    __shared__ int wsum[4];
    __shared__ int sprefix;
    int tid = threadIdx.x, lane = tid & 63, wid = tid >> 6;
    int b = blockIdx.x;
    int base = b * 1024 + tid * 4;
    int4 v = *(int4*)(cur + base);
    int t0 = v.x, t01 = t0 + v.y, t012 = t01 + v.z, tot = t012 + v.w;
    int incl = tot;
    #pragma unroll
    for (int ofs = 1; ofs < 64; ofs <<= 1) {
        int t = __shfl_up(incl, ofs, 64);
        if (lane >= ofs) incl += t;
    }
    if (lane == 63) wsum[wid] = incl;
    __syncthreads();
    if (tid == 0) {
        int run = 0;
        #pragma unroll
        for (int w = 0; w < 4; ++w) { int t = wsum[w]; wsum[w] = run; run += t; }
        // lookback chain
        int segfirst = (b >= 61) ? 61 : (b >= 49) ? 49 : 0;
        int pfx = 0;
        if (b != segfirst) {
            unsigned int f;
            do {
                f = __hip_atomic_load(&flag[b - 1], __ATOMIC_ACQUIRE,
                                      __HIP_MEMORY_SCOPE_AGENT);
            } while (f == 0);
            pfx = (int)(f - 1u);
        }
        __hip_atomic_store(&flag[b], (unsigned int)(pfx + run) + 1u,
                           __ATOMIC_RELEASE, __HIP_MEMORY_SCOPE_AGENT);
        sprefix = pfx;
    }
    __syncthreads();
    int add = sprefix + wsum[wid] + incl - tot;   // exclusive prefix for v.x
    v.x = add; v.y = add + t0; v.z = add + t01; v.w = add + t012;
    *(int4*)(cur + base) = v;
}

// fill: idx[cursor(dst)] = src; afterwards cur[] holds INCLUSIVE offsets
__global__ __launch_bounds__(256) void fill_all(
    const int* __restrict__ s0, const int* __restrict__ s1, const int* __restrict__ s2,
    const int* __restrict__ d0, const int* __restrict__ d1, const int* __restrict__ d2,
    int* __restrict__ cur, int* __restrict__ idx, int E0, int E01, int Etot)
{
    int e = blockIdx.x * 256 + threadIdx.x;
    if (e >= Etot) return;
    int base, d, s, ib;
    if (e < E0)       { base = SEG0; d = d0[e];       s = s0[e];       ib = 0; }
    else if (e < E01) { base = SEG1; d = d1[e - E0];  s = s1[e - E0];  ib = E0; }
    else              { base = SEG2; d = d2[e - E01]; s = s2[e - E01]; ib = E01; }
    int p = atomicAdd(&cur[base + d], 1);
    idx[ib + p] = s;
}

// ---------- fused layer kernel: out = relu(h_self@W1 + mean(h[idx])@W2 + b) --
// 128x256 tile, 512 threads = 8 waves (2 row x 4 col), K=512 (two 256 phases).
// kt<8: A = self rows of h. kt>=8: A-tile chunks GATHERED on the fly from h
// (no mean buffer). 4 consecutive lanes cover one row's 32-wide k-slice ->
// 64B (bf16) / 128B (fp32) contiguous per edge. B = Wt [col][k] bf16.
template<int FINAL, int F32>
__global__ __launch_bounds__(512) void sage_fused(
    const void* __restrict__ hv,
    const int* __restrict__ idx,
    const int* __restrict__ curseg,
    const unsigned short* __restrict__ Wt1,
    const unsigned short* __restrict__ Wt2,
    const float* __restrict__ bias,
    void* __restrict__ outv,
    int M)
{
    __shared__ unsigned short As[128 * 32];   //  8 KB
    __shared__ unsigned short Bs[256 * 32];   // 16 KB

    int tid = threadIdx.x;
    int lane = tid & 63, wid = tid >> 6;
    int wr = wid >> 2, wc = wid & 3;          // 2 x 4 waves
    int m0 = blockIdx.x * 128;
    int l15 = lane & 15, lq = lane >> 4;

    // A-chunk mapping: chunk = tid -> (row ar, 16B-slot ac)
    int ar = tid >> 2, ac = tid & 3;
    int w = m0 + ar; if (w >= M) w = M - 1;
    int e0 = w ? curseg[w - 1] : 0;
    int e1 = curseg[w];
    float rdeg = 1.0f / fmaxf((float)(e1 - e0), 1.0f);

    f32x4 acc[4][4] = {};

    for (int kt = 0; kt < 16; ++kt) {
        int kk = (kt & 7) * 32;
        // ---- B tile 256x32 (16 KB), async ----
        const unsigned short* B = (kt < 8) ? Wt1 : Wt2;
        #pragma unroll
        for (int q = 0; q < 2; ++q) {
            int ch = q * 512 + tid;
            int col = ch >> 2, c = ch & 3;
            const unsigned short* s = B + (size_t)col * 256 + kk + c * 8;
            __builtin_amdgcn_global_load_lds(
                (const __attribute__((address_space(1))) void*)s,
                (__attribute__((address_space(3))) void*)(Bs + ch * 8),
                16, 0, 0);
        }
        // ---- A tile 128x32 (8 KB), 1 chunk (16B out) per thread ----
        if (kt < 8) {
            if (F32) {
                const float* h = (const float*)hv;
                const float* s = h + (size_t)w * 256 + kk + ac * 8;
                float4 u0 = *(const float4*)s;
                float4 u1 = *(const float4*)(s + 4);
                unsigned short rr[8] = {f2bf(u0.x), f2bf(u0.y), f2bf(u0.z), f2bf(u0.w),
                                        f2bf(u1.x), f2bf(u1.y), f2bf(u1.z), f2bf(u1.w)};
                *(uint4*)(As + tid * 8) = *(uint4*)rr;
            } else {
                const unsigned short* h = (const unsigned short*)hv;
                const unsigned short* s = h + (size_t)w * 256 + kk + ac * 8;
                __builtin_amdgcn_global_load_lds(
                    (const __attribute__((address_space(1))) void*)s,
                    (__attribute__((address_space(3))) void*)(As + tid * 8),
                    16, 0, 0);
            }
        } else {
            float a0 = 0.f, a1 = 0.f, a2 = 0.f, a3 = 0.f,
                  a4 = 0.f, a5 = 0.f, a6 = 0.f, a7 = 0.f;
            if (F32) {
                const float* h = (const float*)hv;
                int e = e0;
                for (; e + 1 < e1; e += 2) {
                    int sa = idx[e], sb = idx[e + 1];
                    const float* pa = h + (size_t)sa * 256 + kk + ac * 8;
                    const float* pb = h + (size_t)sb * 256 + kk + ac * 8;
                    float4 x0 = *(const float4*)pa, x1 = *(const float4*)(pa + 4);
                    float4 y0 = *(const float4*)pb, y1 = *(const float4*)(pb + 4);
                    a0 += x0.x + y0.x; a1 += x0.y + y0.y;
                    a2 += x0.z + y0.z; a3 += x0.w + y0.w;
                    a4 += x1.x + y1.x; a5 += x1.y + y1.y;
                    a6 += x1.z + y1.z; a7 += x1.w + y1.w;
                }
                if (e < e1) {
                    const float* pa = h + (size_t)idx[e] * 256 + kk + ac * 8;
                    float4 x0 = *(const float4*)pa, x1 = *(const float4*)(pa + 4);
                    a0 += x0.x; a1 += x0.y; a2 += x0.z; a3 += x0.w;
                    a4 += x1.x; a5 += x1.y; a6 += x1.z; a7 += x1.w;
                }
            } else {
                const unsigned short* h = (const unsigned short*)hv;
                int e = e0;
                for (; e + 1 < e1; e += 2) {
                    int sa = idx[e], sb = idx[e + 1];
                    uint4 u = *(const uint4*)(h + (size_t)sa * 256 + kk + ac * 8);
                    uint4 v = *(const uint4*)(h + (size_t)sb * 256 + kk + ac * 8);
                    a0 += bflo(u.x) + bflo(v.x); a1 += bfhi(u.x) + bfhi(v.x);
                    a2 += bflo(u.y) + bflo(v.y); a3 += bfhi(u.y) + bfhi(v.y);
                    a4 += bflo(u.z) + bflo(v.z); a5 += bfhi(u.z) + bfhi(v.z);
                    a6 += bflo(u.w) + bflo(v.w); a7 += bfhi(u.w) + bfhi(v.w);
                }
                if (e < e1) {
                    uint4 u = *(const uint4*)(h + (size_t)idx[e] * 256 + kk + ac * 8);
                    a0 += bflo(u.x); a1 += bfhi(u.x);
                    a2 += bflo(u.y); a3 += bfhi(u.y);
                    a4 += bflo(u.z); a5 += bfhi(u.z);
                    a6 += bflo(u.w); a7 += bfhi(u.w);
                }
            }
            unsigned short rr[8] = {f2bf(a0 * rdeg), f2bf(a1 * rdeg),
                                    f2bf(a2 * rdeg), f2bf(a3 * rdeg),
                                    f2bf(a4 * rdeg), f2bf(a5 * rdeg),
                                    f2bf(a6 * rdeg), f2bf(a7 * rdeg)};
            *(uint4*)(As + tid * 8) = *(uint4*)rr;
        }
        __syncthreads();

        bf16x8 af[4], bfr[4];
        #pragma unroll
        for (int i = 0; i < 4; ++i) {
            af[i]  = *(const bf16x8*)(As + (wr * 64 + i * 16 + l15) * 32 + lq * 8);
            bfr[i] = *(const bf16x8*)(Bs + (wc * 64 + i * 16 + l15) * 32 + lq * 8);
        }
        #pragma unroll
        for (int mr = 0; mr < 4; ++mr)
            #pragma unroll
            for (int nc = 0; nc < 4; ++nc)
                acc[mr][nc] = __builtin_amdgcn_mfma_f32_16x16x32_bf16(
                    af[mr], bfr[nc], acc[mr][nc], 0, 0, 0);
        __syncthreads();
    }

    // epilogue: bias + relu; C/D layout col=lane&15, row=(lane>>4)*4+reg
    #pragma unroll
    for (int nc = 0; nc < 4; ++nc) {
        int gc = wc * 64 + nc * 16 + l15;
        float bv = bias[gc];
        #pragma unroll
        for (int mr = 0; mr < 4; ++mr) {
            #pragma unroll
            for (int reg = 0; reg < 4; ++reg) {
                int gr = m0 + wr * 64 + mr * 16 + lq * 4 + reg;
                if (gr < M) {
                    float v = fmaxf(acc[mr][nc][reg] + bv, 0.f);
                    if (FINAL) ((float*)outv)[(size_t)gr * 256 + gc] = v;
                    else ((unsigned short*)outv)[(size_t)gr * 256 + gc] = f2bf(v);
                }
            }
        }
    }
}

extern "C" void kernel_launch(void* const* d_in, const int* in_sizes, int n_in,
                              void* d_out, int out_size, void* d_ws, size_t ws_size,
                              hipStream_t stream) {
    const float* x = (const float*)d_in[0];
    const float* Wself[3]  = {(const float*)d_in[1], (const float*)d_in[4], (const float*)d_in[7]};
    const float* Wneigh[3] = {(const float*)d_in[2], (const float*)d_in[5], (const float*)d_in[8]};
    const float* bias[3]   = {(const float*)d_in[3], (const float*)d_in[6], (const float*)d_in[9]};
    const int* src[3] = {(const int*)d_in[10], (const int*)d_in[12], (const int*)d_in[14]};
    const int* dst[3] = {(const int*)d_in[11], (const int*)d_in[13], (const int*)d_in[15]};
    int E[3]    = {in_sizes[10], in_sizes[12], in_sizes[14]};
    int ndst[3] = {50000, 12000, 4000};   // NODE_COUNTS[1..3] fixed by setup_inputs
    int E0 = E[0], E01 = E[0] + E[1], Etot = E[0] + E[1] + E[2];

    // workspace (no mean buffer anymore)
    unsigned short* h1b = (unsigned short*)d_ws;            // 50000*256
    unsigned short* h2b = h1b + (size_t)50000 * D;          // 12000*256
    unsigned short* wt  = h2b + (size_t)12000 * D;          // 6*65536 [col][k]
    int* cur            = (int*)(wt + 6 * 65536);           // CURTOT
    unsigned int* flag  = (unsigned int*)(cur + CURTOT);    // NBLK (pad 80)
    int* idxa           = (int*)(flag + 80);                // Etot (<=660000)

    // zero cur + flags in one memset
    hipMemsetAsync(cur, 0, (CURTOT + 80) * sizeof(int), stream);

    PreArgs pa;
    pa.w[0] = Wself[0]; pa.w[1] = Wneigh[0];
    pa.w[2] = Wself[1]; pa.w[3] = Wneigh[1];
    pa.w[4] = Wself[2]; pa.w[5] = Wneigh[2];
    pa.wt = wt;
    pa.d0 = dst[0]; pa.d1 = dst[1]; pa.d2 = dst[2];
    pa.cur = cur; pa.E0 = E0; pa.E01 = E01; pa.Etot = Etot;
    int cblk = (Etot + 255) / 256;
    fused_pre<<<WBLK + cblk, 256, 0, stream>>>(pa);

    scan_lookback<<<NBLK, 256, 0, stream>>>(cur, flag);

    fill_all<<<(Etot + 255) / 256, 256, 0, stream>>>(src[0], src[1], src[2],
        dst[0], dst[1], dst[2], cur, idxa, E0, E01, Etot);

    // layer 0: self+gather from fp32 x
    sage_fused<0, 1><<<(50000 + 127) / 128, 512, 0, stream>>>(
        x, idxa + 0, cur + SEG0, wt + 0 * 65536, wt + 1 * 65536,
        bias[0], h1b, 50000);
    // layer 1: from bf16 h1
    sage_fused<0, 0><<<(12000 + 127) / 128, 512, 0, stream>>>(
        h1b, idxa + E0, cur + SEG1, wt + 2 * 65536, wt + 3 * 65536,
        bias[1], h2b, 12000);
    // layer 2: from bf16 h2, fp32 output
    sage_fused<1, 0><<<(4000 + 127) / 128, 512, 0, stream>>>(
        h2b, idxa + E01, cur + SEG2, wt + 4 * 65536, wt + 5 * 65536,
        bias[2], d_out, 4000);
}

// Round 9
// 308.947 us; speedup vs baseline: 1.3619x; 1.3619x over previous
//
#include <hip/hip_runtime.h>
#include <stdint.h>

#define D 256

typedef __attribute__((ext_vector_type(8))) short bf16x8;
typedef __attribute__((ext_vector_type(4))) float f32x4;

__device__ inline unsigned short f2bf(float f) {
    union { float f; uint32_t u; } v; v.f = f;
    return (unsigned short)((v.u + 0x7FFFu + ((v.u >> 16) & 1u)) >> 16);
}
__device__ inline float bf2f(unsigned short b) {
    return __uint_as_float(((uint32_t)b) << 16);
}

// segment geometry (padded to 1024-multiples for the block scan)
#define SEG0 0
#define SEG1 50176
#define SEG2 62464
#define CURTOT 66560          // 50176+12288+4096
#define NBLK 65               // seg0 blocks 0-48, seg1 49-60, seg2 61-64

#define WBLK 1536             // 6*65536/256

// ---------- fused preprocessing: weights (PERMUTED) + edge count -------------
// wt layout per W (65536 shorts): tile (nb,kt) = 4096 shorts (512 chunks x 8).
// chunk c: g=c>>6, q=(c>>4)&3, cl=c&15 -> col = nb*128+g*16+cl, k = kt*32+q*8+j.
// This makes GEMM Bs staging linear AND bfr ds_reads canonical (conflict-free).
struct PreArgs {
    const float* w[6];
    unsigned short* wt;
    const int* d0; const int* d1; const int* d2;
    int* cur;
    int E0, E01, Etot;
};

__global__ __launch_bounds__(256) void fused_pre(PreArgs a)
{
    int b = blockIdx.x;
    if (b < WBLK) {
        int t = b * 256 + threadIdx.x;
        int m = t >> 16, e = t & 65535;
        int tile = e >> 12;            // nb*8 + kt
        int nb = tile >> 3, kt = tile & 7;
        int cc = (e >> 3) & 511;
        int j  = e & 7;
        int g = cc >> 6, q = (cc >> 4) & 3, cl = cc & 15;
        int col = nb * 128 + g * 16 + cl;
        int k   = kt * 32 + q * 8 + j;
        a.wt[t] = f2bf(a.w[m][k * 256 + col]);
    } else {
        int e = (b - WBLK) * 256 + threadIdx.x;
        if (e >= a.Etot) return;
        int base, d;
        if (e < a.E0)       { base = SEG0; d = a.d0[e]; }
        else if (e < a.E01) { base = SEG1; d = a.d1[e - a.E0]; }
        else                { base = SEG2; d = a.d2[e - a.E01]; }
        atomicAdd(&a.cur[base + d], 1);
    }
}

// ---------- single-pass segmented scan with decoupled lookback ---------------
__global__ __launch_bounds__(256) void scan_lookback(
    int* __restrict__ cur, unsigned int* __restrict__ flag)
{
    __shared__ int wsum[4];
    __shared__ int sprefix;
    int tid = threadIdx.x, lane = tid & 63, wid = tid >> 6;
    int b = blockIdx.x;
    int base = b * 1024 + tid * 4;
    int4 v = *(int4*)(cur + base);
    int t0 = v.x, t01 = t0 + v.y, t012 = t01 + v.z, tot = t012 + v.w;
    int incl = tot;
    #pragma unroll
    for (int ofs = 1; ofs < 64; ofs <<= 1) {
        int t = __shfl_up(incl, ofs, 64);
        if (lane >= ofs) incl += t;
    }
    if (lane == 63) wsum[wid] = incl;
    __syncthreads();
    if (tid == 0) {
        int run = 0;
        #pragma unroll
        for (int w = 0; w < 4; ++w) { int t = wsum[w]; wsum[w] = run; run += t; }
        int segfirst = (b >= 61) ? 61 : (b >= 49) ? 49 : 0;
        int pfx = 0;
        if (b != segfirst) {
            unsigned int f;
            do {
                f = __hip_atomic_load(&flag[b - 1], __ATOMIC_ACQUIRE,
                                      __HIP_MEMORY_SCOPE_AGENT);
            } while (f == 0);
            pfx = (int)(f - 1u);
        }
        __hip_atomic_store(&flag[b], (unsigned int)(pfx + run) + 1u,
                           __ATOMIC_RELEASE, __HIP_MEMORY_SCOPE_AGENT);
        sprefix = pfx;
    }
    __syncthreads();
    int add = sprefix + wsum[wid] + incl - tot;
    v.x = add; v.y = add + t0; v.z = add + t01; v.w = add + t012;
    *(int4*)(cur + base) = v;
}

// fill: idx[cursor(dst)] = src; afterwards cur[] holds INCLUSIVE offsets
__global__ __launch_bounds__(256) void fill_all(
    const int* __restrict__ s0, const int* __restrict__ s1, const int* __restrict__ s2,
    const int* __restrict__ d0, const int* __restrict__ d1, const int* __restrict__ d2,
    int* __restrict__ cur, int* __restrict__ idx, int E0, int E01, int Etot)
{
    int e = blockIdx.x * 256 + threadIdx.x;
    if (e >= Etot) return;
    int base, d, s, ib;
    if (e < E0)       { base = SEG0; d = d0[e];       s = s0[e];       ib = 0; }
    else if (e < E01) { base = SEG1; d = d1[e - E0];  s = s1[e - E0];  ib = E0; }
    else              { base = SEG2; d = d2[e - E01]; s = s2[e - E01]; ib = E01; }
    int p = atomicAdd(&cur[base + d], 1);
    idx[ib + p] = s;
}

// ---------- gather + mean (one wave per dst row), 4-deep unroll --------------
// REPS>1: instrumentation — rerun the whole body (idempotent) to make this
// dispatch visible in the profile top-5 with counters.
template<int BF16IN, int REPS>
__global__ __launch_bounds__(256) void gather_mean_k(
    const void* __restrict__ hv, const int* __restrict__ idx,
    const int* __restrict__ curseg, unsigned short* __restrict__ mean, int M)
{
    int t = blockIdx.x * blockDim.x + threadIdx.x;
    int w = t >> 6, lane = t & 63;
    if (w >= M) return;
    int e0 = w ? curseg[w - 1] : 0;
    int e1 = curseg[w];
    for (int rep = 0; rep < REPS; ++rep) {
        float4 acc0 = make_float4(0.f, 0.f, 0.f, 0.f);
        float4 acc1 = make_float4(0.f, 0.f, 0.f, 0.f);
        int e = e0;
        if (BF16IN) {
            const unsigned short* h = (const unsigned short*)hv;
            for (; e + 3 < e1; e += 4) {
                int sa = idx[e], sb = idx[e + 1], sc = idx[e + 2], sd = idx[e + 3];
                ushort4 va = *(const ushort4*)(h + (size_t)sa * D + lane * 4);
                ushort4 vb = *(const ushort4*)(h + (size_t)sb * D + lane * 4);
                ushort4 vc = *(const ushort4*)(h + (size_t)sc * D + lane * 4);
                ushort4 vd = *(const ushort4*)(h + (size_t)sd * D + lane * 4);
                acc0.x += bf2f(va.x) + bf2f(vb.x);
                acc0.y += bf2f(va.y) + bf2f(vb.y);
                acc0.z += bf2f(va.z) + bf2f(vb.z);
                acc0.w += bf2f(va.w) + bf2f(vb.w);
                acc1.x += bf2f(vc.x) + bf2f(vd.x);
                acc1.y += bf2f(vc.y) + bf2f(vd.y);
                acc1.z += bf2f(vc.z) + bf2f(vd.z);
                acc1.w += bf2f(vc.w) + bf2f(vd.w);
            }
            for (; e < e1; ++e) {
                int sa = idx[e];
                ushort4 va = *(const ushort4*)(h + (size_t)sa * D + lane * 4);
                acc0.x += bf2f(va.x); acc0.y += bf2f(va.y);
                acc0.z += bf2f(va.z); acc0.w += bf2f(va.w);
            }
        } else {
            const float* h = (const float*)hv;
            for (; e + 3 < e1; e += 4) {
                int sa = idx[e], sb = idx[e + 1], sc = idx[e + 2], sd = idx[e + 3];
                float4 va = *((const float4*)(h + (size_t)sa * D) + lane);
                float4 vb = *((const float4*)(h + (size_t)sb * D) + lane);
                float4 vc = *((const float4*)(h + (size_t)sc * D) + lane);
                float4 vd = *((const float4*)(h + (size_t)sd * D) + lane);
                acc0.x += va.x + vb.x; acc0.y += va.y + vb.y;
                acc0.z += va.z + vb.z; acc0.w += va.w + vb.w;
                acc1.x += vc.x + vd.x; acc1.y += vc.y + vd.y;
                acc1.z += vc.z + vd.z; acc1.w += vc.w + vd.w;
            }
            for (; e < e1; ++e) {
                int sa = idx[e];
                float4 va = *((const float4*)(h + (size_t)sa * D) + lane);
                acc0.x += va.x; acc0.y += va.y; acc0.z += va.z; acc0.w += va.w;
            }
        }
        acc0.x += acc1.x; acc0.y += acc1.y; acc0.z += acc1.z; acc0.w += acc1.w;
        float r = 1.0f / fmaxf((float)(e1 - e0), 1.0f);
        ushort4 o;
        o.x = f2bf(acc0.x * r); o.y = f2bf(acc0.y * r);
        o.z = f2bf(acc0.z * r); o.w = f2bf(acc0.w * r);
        *(ushort4*)(mean + (size_t)w * D + lane * 4) = o;
        if (REPS > 1) asm volatile("" ::: "memory");
    }
}

// ---------- MFMA GEMM: out = relu(A1@W1 + A2@W2 + b) ----------
// 128x128 block tile, 4 waves (2x2) of 64x64, K=512 (two 256 phases).
// B (wt) is pre-permuted: staging linear, bfr reads conflict-free.
template<int FINAL, int A1F32>
__global__ __launch_bounds__(256) void sage_gemm_mfma(
    const void* __restrict__ A1v,
    const unsigned short* __restrict__ A2,
    const unsigned short* __restrict__ Wt1,
    const unsigned short* __restrict__ Wt2,
    const float* __restrict__ bias,
    void* __restrict__ outv,
    int M)
{
    __shared__ unsigned short As[128 * 32];   // 8 KB
    __shared__ unsigned short Bs[128 * 32];   // 8 KB

    int tid = threadIdx.x;
    int lane = tid & 63, wid = tid >> 6;
    int wr = wid >> 1, wc = wid & 1;
    int m0 = blockIdx.x * 128, n0 = blockIdx.y * 128;
    int nb = blockIdx.y;                      // n-block for wt tile addressing
    int l15 = lane & 15, lq = lane >> 4;

    f32x4 acc[4][4] = {};

    for (int kt = 0; kt < 16; ++kt) {
        int kk = (kt & 7) * 32;
        // ---- A tile 128x32 bf16 (8 KB) ----
        if (A1F32 && kt < 8) {
            const float* A = (const float*)A1v;
            #pragma unroll
            for (int q = 0; q < 2; ++q) {
                int ch = q * 256 + tid;          // 0..511 chunks of 16B
                int r = ch >> 2, c16 = ch & 3;
                int gr = m0 + r; if (gr >= M) gr = M - 1;
                const float* s = A + (size_t)gr * 256 + kk + c16 * 8;
                float4 u0 = *(const float4*)s;
                float4 u1 = *(const float4*)(s + 4);
                unsigned short rr[8] = {f2bf(u0.x), f2bf(u0.y), f2bf(u0.z), f2bf(u0.w),
                                        f2bf(u1.x), f2bf(u1.y), f2bf(u1.z), f2bf(u1.w)};
                *(uint4*)(As + ch * 8) = *(uint4*)rr;
            }
        } else {
            const unsigned short* A = (kt < 8) ? (const unsigned short*)A1v : A2;
            #pragma unroll
            for (int q = 0; q < 2; ++q) {
                int ch = q * 256 + tid;
                int r = ch >> 2, c16 = ch & 3;
                int gr = m0 + r; if (gr >= M) gr = M - 1;
                const unsigned short* s = A + (size_t)gr * 256 + kk + c16 * 8;
                __builtin_amdgcn_global_load_lds(
                    (const __attribute__((address_space(1))) void*)s,
                    (__attribute__((address_space(3))) void*)(As + (q * 256 + wid * 64) * 8),
                    16, 0, 0);
            }
        }
        // ---- B tile (8 KB): LINEAR staging from pre-permuted wt ----
        {
            const unsigned short* B = (kt < 8) ? Wt1 : Wt2;
            const unsigned short* tb = B + (size_t)(nb * 8 + (kt & 7)) * 4096;
            #pragma unroll
            for (int q = 0; q < 2; ++q) {
                int ch = q * 256 + tid;
                const unsigned short* s = tb + ch * 8;
                __builtin_amdgcn_global_load_lds(
                    (const __attribute__((address_space(1))) void*)s,
                    (__attribute__((address_space(3))) void*)(Bs + (q * 256 + wid * 64) * 8),
                    16, 0, 0);
            }
        }
        __syncthreads();

        bf16x8 af[4], bfr[4];
        #pragma unroll
        for (int i = 0; i < 4; ++i) {
            af[i]  = *(const bf16x8*)(As + (wr * 64 + i * 16 + l15) * 32 + lq * 8);
            // permuted Bs: group (wc*4+i), position lq*16+l15 == lane (canonical)
            bfr[i] = *(const bf16x8*)(Bs + ((wc * 4 + i) * 64 + lq * 16 + l15) * 8);
        }
        #pragma unroll
        for (int mr = 0; mr < 4; ++mr)
            #pragma unroll
            for (int nc = 0; nc < 4; ++nc)
                acc[mr][nc] = __builtin_amdgcn_mfma_f32_16x16x32_bf16(
                    af[mr], bfr[nc], acc[mr][nc], 0, 0, 0);
        __syncthreads();
    }

    // epilogue: bias + relu; C/D layout col=lane&15, row=(lane>>4)*4+reg
    #pragma unroll
    for (int nc = 0; nc < 4; ++nc) {
        int gc = n0 + wc * 64 + nc * 16 + l15;
        float bv = bias[gc];
        #pragma unroll
        for (int mr = 0; mr < 4; ++mr) {
            #pragma unroll
            for (int reg = 0; reg < 4; ++reg) {
                int gr = m0 + wr * 64 + mr * 16 + lq * 4 + reg;
                if (gr < M) {
                    float v = fmaxf(acc[mr][nc][reg] + bv, 0.f);
                    if (FINAL) ((float*)outv)[(size_t)gr * 256 + gc] = v;
                    else ((unsigned short*)outv)[(size_t)gr * 256 + gc] = f2bf(v);
                }
            }
        }
    }
}

extern "C" void kernel_launch(void* const* d_in, const int* in_sizes, int n_in,
                              void* d_out, int out_size, void* d_ws, size_t ws_size,
                              hipStream_t stream) {
    const float* x = (const float*)d_in[0];
    const float* Wself[3]  = {(const float*)d_in[1], (const float*)d_in[4], (const float*)d_in[7]};
    const float* Wneigh[3] = {(const float*)d_in[2], (const float*)d_in[5], (const float*)d_in[8]};
    const float* bias[3]   = {(const float*)d_in[3], (const float*)d_in[6], (const float*)d_in[9]};
    const int* src[3] = {(const int*)d_in[10], (const int*)d_in[12], (const int*)d_in[14]};
    const int* dst[3] = {(const int*)d_in[11], (const int*)d_in[13], (const int*)d_in[15]};
    int E[3]    = {in_sizes[10], in_sizes[12], in_sizes[14]};
    int E0 = E[0], E01 = E[0] + E[1], Etot = E[0] + E[1] + E[2];

    // workspace
    unsigned short* h1b = (unsigned short*)d_ws;            // 50000*256
    unsigned short* h2b = h1b + (size_t)50000 * D;          // 12000*256
    unsigned short* meanb = h2b + (size_t)12000 * D;        // 50000*256
    unsigned short* wt  = meanb + (size_t)50000 * D;        // 6*65536 permuted
    int* cur            = (int*)(wt + 6 * 65536);           // CURTOT
    unsigned int* flag  = (unsigned int*)(cur + CURTOT);    // NBLK (pad 80)
    int* idxa           = (int*)(flag + 80);                // Etot (<=660000)

    hipMemsetAsync(cur, 0, (CURTOT + 80) * sizeof(int), stream);

    PreArgs pa;
    pa.w[0] = Wself[0]; pa.w[1] = Wneigh[0];
    pa.w[2] = Wself[1]; pa.w[3] = Wneigh[1];
    pa.w[4] = Wself[2]; pa.w[5] = Wneigh[2];
    pa.wt = wt;
    pa.d0 = dst[0]; pa.d1 = dst[1]; pa.d2 = dst[2];
    pa.cur = cur; pa.E0 = E0; pa.E01 = E01; pa.Etot = Etot;
    int cblk = (Etot + 255) / 256;
    fused_pre<<<WBLK + cblk, 256, 0, stream>>>(pa);

    scan_lookback<<<NBLK, 256, 0, stream>>>(cur, flag);

    fill_all<<<(Etot + 255) / 256, 256, 0, stream>>>(src[0], src[1], src[2],
        dst[0], dst[1], dst[2], cur, idxa, E0, E01, Etot);

    // layer 0 gather (fp32 x), REPS=2 for instrumentation visibility
    gather_mean_k<0, 2><<<(50000 * 64 + 255) / 256, 256, 0, stream>>>(
        x, idxa + 0, cur + SEG0, meanb, 50000);
    sage_gemm_mfma<0, 1><<<dim3((50000 + 127) / 128, 2), 256, 0, stream>>>(
        x, meanb, wt + 0 * 65536, wt + 1 * 65536, bias[0], h1b, 50000);

    gather_mean_k<1, 1><<<(12000 * 64 + 255) / 256, 256, 0, stream>>>(
        h1b, idxa + E0, cur + SEG1, meanb, 12000);
    sage_gemm_mfma<0, 0><<<dim3((12000 + 127) / 128, 2), 256, 0, stream>>>(
        h1b, meanb, wt + 2 * 65536, wt + 3 * 65536, bias[1], h2b, 12000);

    gather_mean_k<1, 1><<<(4000 * 64 + 255) / 256, 256, 0, stream>>>(
        h2b, idxa + E01, cur + SEG2, meanb, 4000);
    sage_gemm_mfma<1, 0><<<dim3((4000 + 127) / 128, 2), 256, 0, stream>>>(
        h2b, meanb, wt + 4 * 65536, wt + 5 * 65536, bias[2], d_out, 4000);
}